// Round 1
// baseline (694.949 us; speedup 1.0000x reference)
//
#include <hip/hip_runtime.h>
#include <hip/hip_bf16.h>

#define N_NODES    100000
#define N_EDGES    1200000
#define NUM_GRAPHS 128
#define IN_DIM     5
#define HIDDEN     64
#define M_TILES    (N_NODES / 16)   // 6250 (exact)
#define NI4        (N_EDGES / 4)    // 300000 int4 groups

#define CB    782                   // coarse buckets: ceil(N/128)
#define CBLK  256                   // partition blocks
#define EPB   ((NI4 + CBLK - 1) / CBLK)   // 1172 int4-groups per block
#define ST2   65                    // LDS row stride (floats) for L2 bucket acc

typedef __attribute__((ext_vector_type(8))) short short8;   // 8 bf16 (4 VGPRs)
typedef __attribute__((ext_vector_type(4))) float f32x4;

// fp32 -> bf16 bits (RNE)
__device__ __forceinline__ unsigned short f2bs(float f) {
    union { float f; unsigned u; } v; v.f = f;
    return (unsigned short)((v.u + 0x7FFFu + ((v.u >> 16) & 1u)) >> 16);
}
// bf16 bits -> fp32
__device__ __forceinline__ float bs2f(unsigned short s) {
    union { unsigned u; float f; } v; v.u = ((unsigned)s) << 16;
    return v.f;
}
__device__ __forceinline__ float blo(unsigned p) { return bs2f((unsigned short)(p & 0xffff)); }
__device__ __forceinline__ float bhi(unsigned p) { return bs2f((unsigned short)(p >> 16)); }
__device__ __forceinline__ unsigned pack2(float a, float b) {
    return ((unsigned)f2bs(b) << 16) | (unsigned)f2bs(a);
}

// fp32 (>=0) -> fp8 e4m3 bits, RNE, denorm-exact (magic-multiply trick)
__device__ __forceinline__ unsigned char f2f8(float f) {
    union { float f; unsigned u; } v; v.f = f * 0x1p-120f;
    unsigned u = v.u + 0x7FFFFu + ((v.u >> 20) & 1u);
    return (unsigned char)(u >> 20);
}
// fp8 e4m3 bits -> fp32 (exact inverse)
__device__ __forceinline__ float f82f(unsigned b) {
    union { unsigned u; float f; } v; v.u = (b & 0x7Fu) << 20;
    return v.f * 0x1p120f;
}

// ==================== CSR build: coarse counting sort only ==================
// part entries are PACKED 4B: src (bits 0..16) | (dst & 127) << 17.
// NOTE: fine_sort / ptr / esrc are GONE — the bucket-parallel LDS-atomic
// aggregation kernels only need the coarse 128-node partition.

// ---- Pass A: coarse histogram (dst>>7) + packx fold ------------------------
__global__ void coarse_count(const int* __restrict__ dst, int* __restrict__ gcnt,
                             const float* __restrict__ x, uint4* __restrict__ xb) {
    __shared__ int h[CB];
    int t = threadIdx.x, b = blockIdx.x;
    for (int i = t; i < CB; i += 256) h[i] = 0;
    __syncthreads();
    int i0 = b * EPB, i1 = min(i0 + EPB, NI4);
    for (int i = i0 + t; i < i1; i += 256) {
        int4 d = ((const int4*)dst)[i];
        atomicAdd(&h[d.x >> 7], 1);
        atomicAdd(&h[d.y >> 7], 1);
        atomicAdd(&h[d.z >> 7], 1);
        atomicAdd(&h[d.w >> 7], 1);
    }
    __syncthreads();
    for (int i = t; i < CB; i += 256) gcnt[b * CB + i] = h[i];

    // fold: pack x rows into 16B (5 bf16 + pad) for the layer-1 edge gather
    for (int n = b * 256 + t; n < N_NODES; n += CBLK * 256) {
        const float* xr = x + (size_t)n * IN_DIM;
        uint4 o;
        o.x = pack2(xr[0], xr[1]);
        o.y = pack2(xr[2], xr[3]);
        o.z = pack2(xr[4], 0.0f);
        o.w = 0u;
        xb[n] = o;
    }
}

// ---- Pass B1: per-bucket exclusive scan over the 256 blocks ---------------
__global__ void block_scan(int* __restrict__ gcnt, int* __restrict__ btot) {
    __shared__ int s[CBLK];
    int k = blockIdx.x, t = threadIdx.x;
    int v = gcnt[t * CB + k];
    s[t] = v;
    __syncthreads();
    for (int off = 1; off < CBLK; off <<= 1) {
        int x = (t >= off) ? s[t - off] : 0;
        __syncthreads();
        s[t] += x;
        __syncthreads();
    }
    gcnt[t * CB + k] = s[t] - v;
    if (t == CBLK - 1) btot[k] = s[t];
}

// ---- Pass B2: scan bucket totals -> bstart; also zero add_pool -------------
__global__ void bucket_scan(const int* __restrict__ btot, int* __restrict__ bstart,
                            float* __restrict__ add_pool) {
    __shared__ int s[1024];
    int t = threadIdx.x;
    int v = (t < CB) ? btot[t] : 0;
    s[t] = v;
    __syncthreads();
    for (int off = 1; off < 1024; off <<= 1) {
        int x = (t >= off) ? s[t - off] : 0;
        __syncthreads();
        s[t] += x;
        __syncthreads();
    }
    if (t < CB) bstart[t] = s[t] - v;
    if (t == 0) bstart[CB] = N_EDGES;
    for (int i = t; i < NUM_GRAPHS * HIDDEN; i += 1024) add_pool[i] = 0.0f;
}

// ---- Pass C: partition edges into coarse-bucket order (packed 4B) ----------
__global__ void partition_k(const int* __restrict__ src, const int* __restrict__ dst,
                            const int* __restrict__ gcnt, const int* __restrict__ bstart,
                            int* __restrict__ part) {
    __shared__ int base[CB];
    __shared__ int h[CB];
    int t = threadIdx.x, b = blockIdx.x;
    for (int i = t; i < CB; i += 256) {
        base[i] = bstart[i] + gcnt[b * CB + i];
        h[i] = 0;
    }
    __syncthreads();
    int i0 = b * EPB, i1 = min(i0 + EPB, NI4);
    for (int i = i0 + t; i < i1; i += 256) {
        int4 s4 = ((const int4*)src)[i];
        int4 d4 = ((const int4*)dst)[i];
        int k, r;
        k = d4.x >> 7; r = atomicAdd(&h[k], 1); part[base[k] + r] = s4.x | ((d4.x & 127) << 17);
        k = d4.y >> 7; r = atomicAdd(&h[k], 1); part[base[k] + r] = s4.y | ((d4.y & 127) << 17);
        k = d4.z >> 7; r = atomicAdd(&h[k], 1); part[base[k] + r] = s4.z | ((d4.z & 127) << 17);
        k = d4.w >> 7; r = atomicAdd(&h[k], 1); part[base[k] + r] = s4.w | ((d4.w & 127) << 17);
    }
}

// ==================== GNN compute ===========================================

// ---- Layer 1: bucket-parallel edge accumulation (LDS f32 atomics) + MLP ----
// One block per 128-node bucket. Edge loop is fully lane-parallel (one edge
// per thread, no shuffle trees, no ptr/esrc indirection). 2.5 KB LDS acc.
__global__ void l1_bucket(const uint4* __restrict__ xb,
                          const float* __restrict__ x,
                          const int* __restrict__ part,
                          const int* __restrict__ bstart,
                          const float* __restrict__ w_rel1,
                          const float* __restrict__ b_rel1,
                          const float* __restrict__ w_root1,
                          unsigned short* __restrict__ h1,
                          unsigned char* __restrict__ h1f8) {
    __shared__ float sa[128 * IN_DIM];     // stride 5: gcd(5,32)=1 -> banks spread
    int k = blockIdx.x, t = threadIdx.x;
    for (int i = t; i < 128 * IN_DIM; i += 256) sa[i] = 0.0f;
    __syncthreads();

    int e0 = bstart[k], e1 = bstart[k + 1];
    for (int e = e0 + t; e < e1; e += 256) {
        unsigned p = (unsigned)part[e];
        uint4 xv = xb[p & 0x1FFFFu];
        float* ac = sa + ((p >> 17) & 127u) * IN_DIM;
        atomicAdd(ac + 0, blo(xv.x));
        atomicAdd(ac + 1, bhi(xv.x));
        atomicAdd(ac + 2, blo(xv.y));
        atomicAdd(ac + 3, bhi(xv.y));
        atomicAdd(ac + 4, blo(xv.z));
    }
    __syncthreads();

    // transform: thread t -> output channel (t&63), nodes (t>>6)+4*iter
    int ch = t & 63;
    float wr[IN_DIM], wo[IN_DIM];
#pragma unroll
    for (int kk = 0; kk < IN_DIM; ++kk) {
        wr[kk] = w_rel1[kk * HIDDEN + ch];
        wo[kk] = w_root1[kk * HIDDEN + ch];
    }
    float bias = b_rel1[ch];
    int n0 = k << 7;
    for (int nl = t >> 6; nl < 128; nl += 4) {
        int n = n0 + nl;
        if (n >= N_NODES) break;
        float acc = bias;
#pragma unroll
        for (int kk = 0; kk < IN_DIM; ++kk)
            acc += sa[nl * IN_DIM + kk] * wr[kk] + x[(size_t)n * IN_DIM + kk] * wo[kk];
        float hv = fmaxf(acc, 0.0f);
        h1[(size_t)n * HIDDEN + ch]   = f2bs(hv);
        h1f8[(size_t)n * HIDDEN + ch] = f2f8(hv);
    }
}

// ---- Layer 2: bucket-parallel fp8-row accumulation (LDS f32 atomics) -------
// One block per bucket; 16-lane group per edge reads one 64B fp8 row and
// ds_add_f32's it into the bucket's 128x64 f32 tile (stride-65 pad: bank =
// (dst + ch) & 31 -> ~2-way, free). 2-edge unroll keeps 2 row loads in flight.
__global__ void l2_bucket(const unsigned* __restrict__ h1f8r,   // row = 16 dwords
                          const int* __restrict__ part,
                          const int* __restrict__ bstart,
                          unsigned* __restrict__ agg2u) {       // row = 32 uints (bf16x2)
    __shared__ float sa[128 * ST2];        // 33280 B
    int k = blockIdx.x, t = threadIdx.x;
    int g = t >> 4, ql = t & 15;
    for (int i = t; i < 128 * ST2; i += 256) sa[i] = 0.0f;
    __syncthreads();

    int e0 = bstart[k], e1 = bstart[k + 1];
    int e = e0 + g;
    for (; e + 16 < e1; e += 32) {
        unsigned pa = (unsigned)part[e];
        unsigned pb = (unsigned)part[e + 16];
        unsigned ra = h1f8r[(size_t)(pa & 0x1FFFFu) * 16 + ql];
        unsigned rb = h1f8r[(size_t)(pb & 0x1FFFFu) * 16 + ql];
        float* aa = sa + ((pa >> 17) & 127u) * ST2 + ql * 4;
        float* ab = sa + ((pb >> 17) & 127u) * ST2 + ql * 4;
        atomicAdd(aa + 0, f82f(ra));
        atomicAdd(aa + 1, f82f(ra >> 8));
        atomicAdd(aa + 2, f82f(ra >> 16));
        atomicAdd(aa + 3, f82f(ra >> 24));
        atomicAdd(ab + 0, f82f(rb));
        atomicAdd(ab + 1, f82f(rb >> 8));
        atomicAdd(ab + 2, f82f(rb >> 16));
        atomicAdd(ab + 3, f82f(rb >> 24));
    }
    if (e < e1) {
        unsigned p = (unsigned)part[e];
        unsigned r = h1f8r[(size_t)(p & 0x1FFFFu) * 16 + ql];
        float* ac = sa + ((p >> 17) & 127u) * ST2 + ql * 4;
        atomicAdd(ac + 0, f82f(r));
        atomicAdd(ac + 1, f82f(r >> 8));
        atomicAdd(ac + 2, f82f(r >> 16));
        atomicAdd(ac + 3, f82f(r >> 24));
    }
    __syncthreads();

    // write out bf16 agg2 rows, coalesced: thread -> (node t>>5, ch pair t&31)
    int n0 = k << 7;
    int cp = t & 31;
    for (int nl = t >> 5; nl < 128; nl += 8) {
        int n = n0 + nl;
        if (n >= N_NODES) break;
        float c0 = sa[nl * ST2 + cp * 2];
        float c1 = sa[nl * ST2 + cp * 2 + 1];
        agg2u[(size_t)n * 32 + cp] = pack2(c0, c1);
    }
}

// ---- Layer 2 transform via MFMA, FUSED with add-pool -----------------------
__global__ void mlp2_pool(const unsigned short* __restrict__ agg2,
                          const unsigned short* __restrict__ h1,
                          const float* __restrict__ w_rel2,
                          const float* __restrict__ b_rel2,
                          const float* __restrict__ w_root2,
                          const int* __restrict__ batch,
                          float* __restrict__ add_pool) {
    int lane = threadIdx.x & 63;
    int wv   = threadIdx.x >> 6;
    int row  = lane & 15;
    int quad = lane >> 4;
    int n    = wv * 16 + row;           // this lane's output column

    short8 bwr[2], bwo[2];
#pragma unroll
    for (int s = 0; s < 2; ++s)
#pragma unroll
        for (int j = 0; j < 8; ++j) {
            int k = 32 * s + quad * 8 + j;
            bwr[s][j] = (short)f2bs(w_rel2[k * HIDDEN + n]);
            bwo[s][j] = (short)f2bs(w_root2[k * HIDDEN + n]);
        }
    float bias = b_rel2[n];

    for (int t = blockIdx.x; t < M_TILES; t += gridDim.x) {
        int m0 = t * 16;
        size_t rbase = (size_t)(m0 + row) * HIDDEN;
        short8 aa0 = *(const short8*)(agg2 + rbase + quad * 8);
        short8 aa1 = *(const short8*)(agg2 + rbase + 32 + quad * 8);
        short8 ah0 = *(const short8*)(h1   + rbase + quad * 8);
        short8 ah1 = *(const short8*)(h1   + rbase + 32 + quad * 8);

        f32x4 acc = {bias, bias, bias, bias};
        acc = __builtin_amdgcn_mfma_f32_16x16x32_bf16(aa0, bwr[0], acc, 0, 0, 0);
        acc = __builtin_amdgcn_mfma_f32_16x16x32_bf16(aa1, bwr[1], acc, 0, 0, 0);
        acc = __builtin_amdgcn_mfma_f32_16x16x32_bf16(ah0, bwo[0], acc, 0, 0, 0);
        acc = __builtin_amdgcn_mfma_f32_16x16x32_bf16(ah1, bwo[1], acc, 0, 0, 0);

        float hv0 = fmaxf(acc[0], 0.0f), hv1 = fmaxf(acc[1], 0.0f);
        float hv2 = fmaxf(acc[2], 0.0f), hv3 = fmaxf(acc[3], 0.0f);

        int gLo = batch[m0], gHi = batch[m0 + 15];
        if (gLo == gHi) {
            float s = (hv0 + hv1) + (hv2 + hv3);
            s += __shfl_xor(s, 16, 64);
            s += __shfl_xor(s, 32, 64);
            if (quad == 0)
                atomicAdd(&add_pool[gLo * HIDDEN + n], s);
        } else {
            int m = m0 + quad * 4;
            atomicAdd(&add_pool[batch[m]     * HIDDEN + n], hv0);
            atomicAdd(&add_pool[batch[m + 1] * HIDDEN + n], hv1);
            atomicAdd(&add_pool[batch[m + 2] * HIDDEN + n], hv2);
            atomicAdd(&add_pool[batch[m + 3] * HIDDEN + n], hv3);
        }
    }
}

// ---- MLP head: one block (64 threads) per graph ----------------------------
__device__ __forceinline__ int lower_bound_i(const int* a, int n, int v) {
    int lo = 0, hi = n;
    while (lo < hi) { int mid = (lo + hi) >> 1; if (a[mid] < v) lo = mid + 1; else hi = mid; }
    return lo;
}

__global__ void head_mlp(const float* __restrict__ add_pool,
                         const int* __restrict__ batch,
                         const float* __restrict__ w_h1,
                         const float* __restrict__ b_h1,
                         const float* __restrict__ w_h2,
                         const float* __restrict__ b_h2,
                         float* __restrict__ out) {
    int g = blockIdx.x, t = threadIdx.x;

    __shared__ int s_cnt;
    if (t == 0) {
        int start = lower_bound_i(batch, N_NODES, g);
        int end   = lower_bound_i(batch, N_NODES, g + 1);
        s_cnt = end - start;
    }
    __syncthreads();
    float cnt = fmaxf((float)s_cnt, 1.0f);

    __shared__ float sg[2 * HIDDEN];
    float add = add_pool[(size_t)g * HIDDEN + t];
    sg[t]          = add / cnt;   // mean_pool
    sg[HIDDEN + t] = add;         // add_pool
    __syncthreads();

    float hid = b_h1[t];
#pragma unroll 16
    for (int i = 0; i < 2 * HIDDEN; ++i)
        hid += sg[i] * w_h1[i * HIDDEN + t];
    hid = fmaxf(hid, 0.0f);

    float res = hid * w_h2[t];
    for (int off = 32; off > 0; off >>= 1)
        res += __shfl_down(res, off, 64);
    if (t == 0) out[g] = res + b_h2[0];
}

extern "C" void kernel_launch(void* const* d_in, const int* in_sizes, int n_in,
                              void* d_out, int out_size, void* d_ws, size_t ws_size,
                              hipStream_t stream) {
    const float* x       = (const float*)d_in[0];
    const int*   ei      = (const int*)d_in[1];
    const int*   src     = ei;
    const int*   dst     = ei + N_EDGES;
    const int*   batch   = (const int*)d_in[2];
    const float* w_rel1  = (const float*)d_in[3];
    const float* b_rel1  = (const float*)d_in[4];
    const float* w_root1 = (const float*)d_in[5];
    const float* w_rel2  = (const float*)d_in[6];
    const float* b_rel2  = (const float*)d_in[7];
    const float* w_root2 = (const float*)d_in[8];
    const float* w_h1    = (const float*)d_in[9];
    const float* b_h1    = (const float*)d_in[10];
    const float* w_h2    = (const float*)d_in[11];
    const float* b_h2    = (const float*)d_in[12];
    float* out = (float*)d_out;

    int* base = (int*)d_ws;
    int*   gcnt     = base;                                   // CBLK*CB
    int*   btot     = gcnt + ((CBLK * CB + 3) & ~3);          // CB
    int*   bstart   = btot + ((CB + 3) & ~3);                 // CB+1
    float* add_pool = (float*)(bstart + ((CB + 1 + 3) & ~3)); // 128*64 f32
    int*   part     = (int*)(add_pool + NUM_GRAPHS * HIDDEN); // E packed ints
    unsigned short* h1   = (unsigned short*)(part + N_EDGES); // N*64 bf16
    unsigned short* agg2 = h1 + (size_t)N_NODES * HIDDEN;     // N*64 bf16
    unsigned char*  h1f8 = (unsigned char*)(agg2 + (size_t)N_NODES * HIDDEN); // N*64 fp8
    uint4*          xb   = (uint4*)(h1f8 + (size_t)N_NODES * HIDDEN);         // N*16B

    // ---- CSR build (coarse partition only; fine_sort eliminated) ----
    coarse_count<<<CBLK, 256, 0, stream>>>(dst, gcnt, x, xb);
    block_scan<<<CB, CBLK, 0, stream>>>(gcnt, btot);
    bucket_scan<<<1, 1024, 0, stream>>>(btot, bstart, add_pool);
    partition_k<<<CBLK, 256, 0, stream>>>(src, dst, gcnt, bstart, part);

    // ---- Layer 1: bucket-parallel LDS-atomic aggregation + transform ----
    l1_bucket<<<CB, 256, 0, stream>>>(xb, x, part, bstart, w_rel1, b_rel1, w_root1, h1, h1f8);
    // ---- Layer 2: bucket-parallel LDS-atomic aggregation (fp8 rows) ----
    l2_bucket<<<CB, 256, 0, stream>>>((const unsigned*)h1f8, part, bstart, (unsigned*)agg2);
    // ---- Layer 2 transform (MFMA) + add-pool ----
    mlp2_pool<<<2048, 256, 0, stream>>>(agg2, h1, w_rel2, b_rel2, w_root2, batch, add_pool);
    // ---- Head ----
    head_mlp<<<NUM_GRAPHS, 64, 0, stream>>>(add_pool, batch, w_h1, b_h1, w_h2, b_h2, out);
}

// Round 2
// 553.184 us; speedup vs baseline: 1.2563x; 1.2563x over previous
//
#include <hip/hip_runtime.h>
#include <hip/hip_bf16.h>

#define N_NODES    100000
#define N_EDGES    1200000
#define NUM_GRAPHS 128
#define IN_DIM     5
#define HIDDEN     64
#define M_TILES    (N_NODES / 16)   // 6250 (exact)
#define NI4        (N_EDGES / 4)    // 300000 int4 groups

#define CBLK  256                   // edge-chunk blocks
#define EPB   ((NI4 + CBLK - 1) / CBLK)   // int4-groups per block
#define SCAN_CH 98                  // 1024*98 = 100352 >= N_NODES+1

typedef __attribute__((ext_vector_type(8))) short short8;   // 8 bf16 (4 VGPRs)
typedef __attribute__((ext_vector_type(4))) float f32x4;

// fp32 -> bf16 bits (RNE)
__device__ __forceinline__ unsigned short f2bs(float f) {
    union { float f; unsigned u; } v; v.f = f;
    return (unsigned short)((v.u + 0x7FFFu + ((v.u >> 16) & 1u)) >> 16);
}
// bf16 bits -> fp32
__device__ __forceinline__ float bs2f(unsigned short s) {
    union { unsigned u; float f; } v; v.u = ((unsigned)s) << 16;
    return v.f;
}
__device__ __forceinline__ float blo(unsigned p) { return bs2f((unsigned short)(p & 0xffff)); }
__device__ __forceinline__ float bhi(unsigned p) { return bs2f((unsigned short)(p >> 16)); }
__device__ __forceinline__ unsigned pack2(float a, float b) {
    return ((unsigned)f2bs(b) << 16) | (unsigned)f2bs(a);
}

// fp32 (>=0) -> fp8 e4m3 bits, RNE, denorm-exact (magic-multiply trick)
__device__ __forceinline__ unsigned char f2f8(float f) {
    union { float f; unsigned u; } v; v.f = f * 0x1p-120f;
    unsigned u = v.u + 0x7FFFFu + ((v.u >> 20) & 1u);
    return (unsigned char)(u >> 20);
}
// fp8 e4m3 bits -> fp32 (exact inverse)
__device__ __forceinline__ float f82f(unsigned b) {
    union { unsigned u; float f; } v; v.u = (b & 0x7Fu) << 20;
    return v.f * 0x1p120f;
}

// ==================== CSR build: direct (global atomics, no LDS atomics) ====

// ---- Pass 0: zero degree array -------------------------------------------
__global__ void zero_k(int* __restrict__ deg) {
    int i = blockIdx.x * blockDim.x + threadIdx.x;
    if (i <= N_NODES) deg[i] = 0;
}

// ---- Pass 1: degree count (global atomics, ~12 per address) + xb pack -----
__global__ void deg_xb(const int* __restrict__ dst, int* __restrict__ deg,
                       const float* __restrict__ x, uint4* __restrict__ xb) {
    int t = threadIdx.x, b = blockIdx.x;
    int i0 = b * EPB, i1 = min(i0 + EPB, NI4);
    for (int i = i0 + t; i < i1; i += 256) {
        int4 d = ((const int4*)dst)[i];
        atomicAdd(&deg[d.x], 1);
        atomicAdd(&deg[d.y], 1);
        atomicAdd(&deg[d.z], 1);
        atomicAdd(&deg[d.w], 1);
    }
    // fold: pack x rows into 16B (5 bf16 + pad) for the layer-1 edge gather
    for (int n = b * 256 + t; n < N_NODES; n += CBLK * 256) {
        const float* xr = x + (size_t)n * IN_DIM;
        uint4 o;
        o.x = pack2(xr[0], xr[1]);
        o.y = pack2(xr[2], xr[3]);
        o.z = pack2(xr[4], 0.0f);
        o.w = 0u;
        xb[n] = o;
    }
}

// ---- Pass 2: single-block scan deg -> ptr, init cur=ptr, zero add_pool -----
__global__ void scan_ptr(const int* __restrict__ deg, int* __restrict__ ptr,
                         int* __restrict__ cur, float* __restrict__ add_pool) {
    __shared__ int s[1024];
    int t = threadIdx.x;
    int base = t * SCAN_CH;
    int sum = 0;
    for (int j = 0; j < SCAN_CH; ++j) {
        int idx = base + j;
        if (idx < N_NODES) sum += deg[idx];
    }
    s[t] = sum;
    __syncthreads();
    for (int off = 1; off < 1024; off <<= 1) {
        int v = (t >= off) ? s[t - off] : 0;
        __syncthreads();
        s[t] += v;
        __syncthreads();
    }
    int running = s[t] - sum;   // exclusive prefix of this thread's chunk
    for (int j = 0; j < SCAN_CH; ++j) {
        int idx = base + j;
        if (idx < N_NODES) {
            ptr[idx] = running;
            cur[idx] = running;   // scatter cursor starts at row base
            running += deg[idx];
        }
    }
    if (t == 1023) ptr[N_NODES] = N_EDGES;
    for (int i = t; i < NUM_GRAPHS * HIDDEN; i += 1024) add_pool[i] = 0.0f;
}

// ---- Pass 3: scatter edges into per-node lists (atomic-return cursor) ------
__global__ void scatter_k(const int* __restrict__ src, const int* __restrict__ dst,
                          int* __restrict__ cur, int* __restrict__ esrc) {
    int t = threadIdx.x, b = blockIdx.x;
    int i0 = b * EPB, i1 = min(i0 + EPB, NI4);
    for (int i = i0 + t; i < i1; i += 256) {
        int4 s4 = ((const int4*)src)[i];
        int4 d4 = ((const int4*)dst)[i];
        int r;
        r = atomicAdd(&cur[d4.x], 1); esrc[r] = s4.x;
        r = atomicAdd(&cur[d4.y], 1); esrc[r] = s4.y;
        r = atomicAdd(&cur[d4.z], 1); esrc[r] = s4.z;
        r = atomicAdd(&cur[d4.w], 1); esrc[r] = s4.w;
    }
}

// ==================== GNN compute ===========================================

// ---- Layer 1: 16-lane-group gather (4 nodes/wave) + transform --------------
// Group of 16 lanes owns one node: lane ql handles edges ql, ql+16, ... then
// a 4-level butterfly reduces IN_DIM sums; each lane emits 4 output channels.
__global__ void gather_mlp1(const uint4* __restrict__ xb,
                            const float* __restrict__ x,
                            const int* __restrict__ ptr,
                            const int* __restrict__ esrc,
                            const float* __restrict__ w_rel1,
                            const float* __restrict__ b_rel1,
                            const float* __restrict__ w_root1,
                            unsigned short* __restrict__ h1,
                            unsigned char* __restrict__ h1f8) {
    int t    = threadIdx.x;
    int ql   = t & 15;
    int grp  = (blockIdx.x * blockDim.x + t) >> 4;
    int ngrp = (gridDim.x * blockDim.x) >> 4;

    float wr[IN_DIM][4], wo[IN_DIM][4], bias[4];
#pragma unroll
    for (int j = 0; j < 4; ++j) {
        int ch = ql * 4 + j;
        bias[j] = b_rel1[ch];
#pragma unroll
        for (int k = 0; k < IN_DIM; ++k) {
            wr[k][j] = w_rel1[k * HIDDEN + ch];
            wo[k][j] = w_root1[k * HIDDEN + ch];
        }
    }

    for (int n = grp; n < N_NODES; n += ngrp) {
        int start = ptr[n], end = ptr[n + 1];
        float a[IN_DIM] = {0.f, 0.f, 0.f, 0.f, 0.f};
        for (int e = start + ql; e < end; e += 16) {
            uint4 p = xb[esrc[e]];
            a[0] += blo(p.x); a[1] += bhi(p.x);
            a[2] += blo(p.y); a[3] += bhi(p.y);
            a[4] += blo(p.z);
        }
#pragma unroll
        for (int k = 0; k < IN_DIM; ++k) {
            a[k] += __shfl_xor(a[k], 1, 64);
            a[k] += __shfl_xor(a[k], 2, 64);
            a[k] += __shfl_xor(a[k], 4, 64);
            a[k] += __shfl_xor(a[k], 8, 64);
        }
        float xr[IN_DIM];
#pragma unroll
        for (int k = 0; k < IN_DIM; ++k) xr[k] = x[(size_t)n * IN_DIM + k];

        unsigned short hv[4];
        unsigned char  hf[4];
#pragma unroll
        for (int j = 0; j < 4; ++j) {
            float acc = bias[j];
#pragma unroll
            for (int k = 0; k < IN_DIM; ++k)
                acc += a[k] * wr[k][j] + xr[k] * wo[k][j];
            float h = fmaxf(acc, 0.0f);
            hv[j] = f2bs(h);
            hf[j] = f2f8(h);
        }
        ushort4 v4; v4.x = hv[0]; v4.y = hv[1]; v4.z = hv[2]; v4.w = hv[3];
        *(ushort4*)(h1 + (size_t)n * HIDDEN + ql * 4) = v4;
        uchar4 c4; c4.x = hf[0]; c4.y = hf[1]; c4.z = hf[2]; c4.w = hf[3];
        *(uchar4*)(h1f8 + (size_t)n * HIDDEN + ql * 4) = c4;
    }
}

// ---- Layer 2: 16-lane-group fp8-row gather (4 nodes/wave, NO shuffles) -----
// Lane ql owns dword ql of the 64B fp8 row end-to-end; 2-edge unroll keeps
// 8 independent row loads in flight per wave.
__global__ void gather2_fp8(const unsigned* __restrict__ rows,   // row = 16 dwords
                            const int* __restrict__ ptr,
                            const int* __restrict__ esrc,
                            uint2* __restrict__ agg2) {          // row = 16 uint2
    int t    = threadIdx.x;
    int ql   = t & 15;
    int grp  = (blockIdx.x * blockDim.x + t) >> 4;
    int ngrp = (gridDim.x * blockDim.x) >> 4;

    for (int n = grp; n < N_NODES; n += ngrp) {
        int start = ptr[n], end = ptr[n + 1];
        float4 a = {0.f, 0.f, 0.f, 0.f};
        float4 b = {0.f, 0.f, 0.f, 0.f};
        int e = start;
        for (; e + 1 < end; e += 2) {
            int s0 = esrc[e], s1 = esrc[e + 1];
            unsigned r0 = rows[(size_t)s0 * 16 + ql];
            unsigned r1 = rows[(size_t)s1 * 16 + ql];
            a.x += f82f(r0); a.y += f82f(r0 >> 8); a.z += f82f(r0 >> 16); a.w += f82f(r0 >> 24);
            b.x += f82f(r1); b.y += f82f(r1 >> 8); b.z += f82f(r1 >> 16); b.w += f82f(r1 >> 24);
        }
        if (e < end) {
            unsigned r0 = rows[(size_t)esrc[e] * 16 + ql];
            a.x += f82f(r0); a.y += f82f(r0 >> 8); a.z += f82f(r0 >> 16); a.w += f82f(r0 >> 24);
        }
        a.x += b.x; a.y += b.y; a.z += b.z; a.w += b.w;
        uint2 o;
        o.x = pack2(a.x, a.y);
        o.y = pack2(a.z, a.w);
        agg2[(size_t)n * 16 + ql] = o;   // 128B contiguous per node row
    }
}

// ---- Layer 2 transform via MFMA, FUSED with add-pool -----------------------
__global__ void mlp2_pool(const unsigned short* __restrict__ agg2,
                          const unsigned short* __restrict__ h1,
                          const float* __restrict__ w_rel2,
                          const float* __restrict__ b_rel2,
                          const float* __restrict__ w_root2,
                          const int* __restrict__ batch,
                          float* __restrict__ add_pool) {
    int lane = threadIdx.x & 63;
    int wv   = threadIdx.x >> 6;
    int row  = lane & 15;
    int quad = lane >> 4;
    int n    = wv * 16 + row;           // this lane's output column

    short8 bwr[2], bwo[2];
#pragma unroll
    for (int s = 0; s < 2; ++s)
#pragma unroll
        for (int j = 0; j < 8; ++j) {
            int k = 32 * s + quad * 8 + j;
            bwr[s][j] = (short)f2bs(w_rel2[k * HIDDEN + n]);
            bwo[s][j] = (short)f2bs(w_root2[k * HIDDEN + n]);
        }
    float bias = b_rel2[n];

    for (int t = blockIdx.x; t < M_TILES; t += gridDim.x) {
        int m0 = t * 16;
        size_t rbase = (size_t)(m0 + row) * HIDDEN;
        short8 aa0 = *(const short8*)(agg2 + rbase + quad * 8);
        short8 aa1 = *(const short8*)(agg2 + rbase + 32 + quad * 8);
        short8 ah0 = *(const short8*)(h1   + rbase + quad * 8);
        short8 ah1 = *(const short8*)(h1   + rbase + 32 + quad * 8);

        f32x4 acc = {bias, bias, bias, bias};
        acc = __builtin_amdgcn_mfma_f32_16x16x32_bf16(aa0, bwr[0], acc, 0, 0, 0);
        acc = __builtin_amdgcn_mfma_f32_16x16x32_bf16(aa1, bwr[1], acc, 0, 0, 0);
        acc = __builtin_amdgcn_mfma_f32_16x16x32_bf16(ah0, bwo[0], acc, 0, 0, 0);
        acc = __builtin_amdgcn_mfma_f32_16x16x32_bf16(ah1, bwo[1], acc, 0, 0, 0);

        float hv0 = fmaxf(acc[0], 0.0f), hv1 = fmaxf(acc[1], 0.0f);
        float hv2 = fmaxf(acc[2], 0.0f), hv3 = fmaxf(acc[3], 0.0f);

        int gLo = batch[m0], gHi = batch[m0 + 15];
        if (gLo == gHi) {
            float s = (hv0 + hv1) + (hv2 + hv3);
            s += __shfl_xor(s, 16, 64);
            s += __shfl_xor(s, 32, 64);
            if (quad == 0)
                atomicAdd(&add_pool[gLo * HIDDEN + n], s);
        } else {
            int m = m0 + quad * 4;
            atomicAdd(&add_pool[batch[m]     * HIDDEN + n], hv0);
            atomicAdd(&add_pool[batch[m + 1] * HIDDEN + n], hv1);
            atomicAdd(&add_pool[batch[m + 2] * HIDDEN + n], hv2);
            atomicAdd(&add_pool[batch[m + 3] * HIDDEN + n], hv3);
        }
    }
}

// ---- MLP head: one block (64 threads) per graph ----------------------------
__device__ __forceinline__ int lower_bound_i(const int* a, int n, int v) {
    int lo = 0, hi = n;
    while (lo < hi) { int mid = (lo + hi) >> 1; if (a[mid] < v) lo = mid + 1; else hi = mid; }
    return lo;
}

__global__ void head_mlp(const float* __restrict__ add_pool,
                         const int* __restrict__ batch,
                         const float* __restrict__ w_h1,
                         const float* __restrict__ b_h1,
                         const float* __restrict__ w_h2,
                         const float* __restrict__ b_h2,
                         float* __restrict__ out) {
    int g = blockIdx.x, t = threadIdx.x;

    __shared__ int s_cnt;
    if (t == 0) {
        int start = lower_bound_i(batch, N_NODES, g);
        int end   = lower_bound_i(batch, N_NODES, g + 1);
        s_cnt = end - start;
    }
    __syncthreads();
    float cnt = fmaxf((float)s_cnt, 1.0f);

    __shared__ float sg[2 * HIDDEN];
    float add = add_pool[(size_t)g * HIDDEN + t];
    sg[t]          = add / cnt;   // mean_pool
    sg[HIDDEN + t] = add;         // add_pool
    __syncthreads();

    float hid = b_h1[t];
#pragma unroll 16
    for (int i = 0; i < 2 * HIDDEN; ++i)
        hid += sg[i] * w_h1[i * HIDDEN + t];
    hid = fmaxf(hid, 0.0f);

    float res = hid * w_h2[t];
    for (int off = 32; off > 0; off >>= 1)
        res += __shfl_down(res, off, 64);
    if (t == 0) out[g] = res + b_h2[0];
}

extern "C" void kernel_launch(void* const* d_in, const int* in_sizes, int n_in,
                              void* d_out, int out_size, void* d_ws, size_t ws_size,
                              hipStream_t stream) {
    const float* x       = (const float*)d_in[0];
    const int*   ei      = (const int*)d_in[1];
    const int*   src     = ei;
    const int*   dst     = ei + N_EDGES;
    const int*   batch   = (const int*)d_in[2];
    const float* w_rel1  = (const float*)d_in[3];
    const float* b_rel1  = (const float*)d_in[4];
    const float* w_root1 = (const float*)d_in[5];
    const float* w_rel2  = (const float*)d_in[6];
    const float* b_rel2  = (const float*)d_in[7];
    const float* w_root2 = (const float*)d_in[8];
    const float* w_h1    = (const float*)d_in[9];
    const float* b_h1    = (const float*)d_in[10];
    const float* w_h2    = (const float*)d_in[11];
    const float* b_h2    = (const float*)d_in[12];
    float* out = (float*)d_out;

    int* base = (int*)d_ws;
    int*   deg      = base;                                      // N+1
    int*   ptr      = deg + ((N_NODES + 1 + 3) & ~3);            // N+1
    int*   cur      = ptr + ((N_NODES + 1 + 3) & ~3);            // N
    float* add_pool = (float*)(cur + ((N_NODES + 3) & ~3));      // 128*64 f32
    int*   esrc     = (int*)(add_pool + NUM_GRAPHS * HIDDEN);    // E
    unsigned short* h1   = (unsigned short*)(esrc + N_EDGES);    // N*64 bf16
    unsigned short* agg2 = h1 + (size_t)N_NODES * HIDDEN;        // N*64 bf16
    unsigned char*  h1f8 = (unsigned char*)(agg2 + (size_t)N_NODES * HIDDEN); // N*64 fp8
    uint4*          xb   = (uint4*)(h1f8 + (size_t)N_NODES * HIDDEN);         // N*16B

    // ---- CSR build: direct, 4 dispatches, no LDS atomics ----
    zero_k<<<(N_NODES + 1 + 1023) / 1024, 1024, 0, stream>>>(deg);
    deg_xb<<<CBLK, 256, 0, stream>>>(dst, deg, x, xb);
    scan_ptr<<<1, 1024, 0, stream>>>(deg, ptr, cur, add_pool);
    scatter_k<<<CBLK, 256, 0, stream>>>(src, dst, cur, esrc);

    // ---- Layer 1 (16-lane groups, 4 nodes/wave) ----
    gather_mlp1<<<2048, 256, 0, stream>>>(xb, x, ptr, esrc, w_rel1, b_rel1, w_root1, h1, h1f8);
    // ---- Layer 2 gather (16-lane groups, channel-owned lanes) ----
    gather2_fp8<<<2048, 256, 0, stream>>>((const unsigned*)h1f8, ptr, esrc, (uint2*)agg2);
    // ---- Layer 2 transform (MFMA) + add-pool ----
    mlp2_pool<<<2048, 256, 0, stream>>>(agg2, h1, w_rel2, b_rel2, w_root2, batch, add_pool);
    // ---- Head ----
    head_mlp<<<NUM_GRAPHS, 64, 0, stream>>>(add_pool, batch, w_h1, b_h1, w_h2, b_h2, out);
}

// Round 3
// 304.155 us; speedup vs baseline: 2.2849x; 1.8188x over previous
//
#include <hip/hip_runtime.h>
#include <hip/hip_bf16.h>

#define N_NODES    100000
#define N_EDGES    1200000
#define NUM_GRAPHS 128
#define IN_DIM     5
#define HIDDEN     64
#define M_TILES    (N_NODES / 16)   // 6250 (exact)
#define NI4        (N_EDGES / 4)    // 300000 int4 groups

#define CBLK  256                   // edge-chunk blocks
#define EPB   ((NI4 + CBLK - 1) / CBLK)   // int4-groups per block
#define SB    98                    // scan blocks: 98*1024 = 100352 >= N_NODES+1

typedef __attribute__((ext_vector_type(8))) short short8;   // 8 bf16 (4 VGPRs)
typedef __attribute__((ext_vector_type(4))) float f32x4;

// fp32 -> bf16 bits (RNE)
__device__ __forceinline__ unsigned short f2bs(float f) {
    union { float f; unsigned u; } v; v.f = f;
    return (unsigned short)((v.u + 0x7FFFu + ((v.u >> 16) & 1u)) >> 16);
}
// bf16 bits -> fp32
__device__ __forceinline__ float bs2f(unsigned short s) {
    union { unsigned u; float f; } v; v.u = ((unsigned)s) << 16;
    return v.f;
}
__device__ __forceinline__ float blo(unsigned p) { return bs2f((unsigned short)(p & 0xffff)); }
__device__ __forceinline__ float bhi(unsigned p) { return bs2f((unsigned short)(p >> 16)); }
__device__ __forceinline__ unsigned pack2(float a, float b) {
    return ((unsigned)f2bs(b) << 16) | (unsigned)f2bs(a);
}

// fp32 (>=0) -> fp8 e4m3 bits, RNE, denorm-exact (magic-multiply trick)
__device__ __forceinline__ unsigned char f2f8(float f) {
    union { float f; unsigned u; } v; v.f = f * 0x1p-120f;
    unsigned u = v.u + 0x7FFFFu + ((v.u >> 20) & 1u);
    return (unsigned char)(u >> 20);
}
// fp8 e4m3 bits -> fp32 (exact inverse)
__device__ __forceinline__ float f82f(unsigned b) {
    union { unsigned u; float f; } v; v.u = (b & 0x7Fu) << 20;
    return v.f * 0x1p120f;
}

// ==================== CSR build: direct (global atomics) ====================

// ---- Pass 0: zero degree array -------------------------------------------
__global__ void zero_k(int* __restrict__ deg) {
    int i = blockIdx.x * blockDim.x + threadIdx.x;
    if (i <= N_NODES) deg[i] = 0;
}

// ---- Pass 1: degree count (global atomics, ~12 per address) + xb pack -----
__global__ void deg_xb(const int* __restrict__ dst, int* __restrict__ deg,
                       const float* __restrict__ x, uint4* __restrict__ xb) {
    int t = threadIdx.x, b = blockIdx.x;
    int i0 = b * EPB, i1 = min(i0 + EPB, NI4);
    for (int i = i0 + t; i < i1; i += 256) {
        int4 d = ((const int4*)dst)[i];
        atomicAdd(&deg[d.x], 1);
        atomicAdd(&deg[d.y], 1);
        atomicAdd(&deg[d.z], 1);
        atomicAdd(&deg[d.w], 1);
    }
    // fold: pack x rows into 16B (5 bf16 + pad) for the layer-1 edge gather
    for (int n = b * 256 + t; n < N_NODES; n += CBLK * 256) {
        const float* xr = x + (size_t)n * IN_DIM;
        uint4 o;
        o.x = pack2(xr[0], xr[1]);
        o.y = pack2(xr[2], xr[3]);
        o.z = pack2(xr[4], 0.0f);
        o.w = 0u;
        xb[n] = o;
    }
}

// ---- Pass 2a: per-block LDS scan -> local exclusive prefix + block total ---
__global__ void scan1(const int* __restrict__ deg, int* __restrict__ ptr,
                      int* __restrict__ bsum) {
    __shared__ int s[1024];
    int t = threadIdx.x, b = blockIdx.x;
    int idx = b * 1024 + t;
    int v = (idx < N_NODES) ? deg[idx] : 0;
    s[t] = v;
    __syncthreads();
    for (int off = 1; off < 1024; off <<= 1) {
        int u = (t >= off) ? s[t - off] : 0;
        __syncthreads();
        s[t] += u;
        __syncthreads();
    }
    if (idx <= N_NODES) ptr[idx] = s[t] - v;   // block-local exclusive
    if (t == 1023) bsum[b] = s[t];
}

// ---- Pass 2b: scan the 98 block totals (1 tiny block) + zero add_pool ------
__global__ void scan2(int* __restrict__ bsum, float* __restrict__ add_pool) {
    __shared__ int s[256];
    int t = threadIdx.x;
    int v = (t < SB) ? bsum[t] : 0;
    s[t] = v;
    __syncthreads();
    for (int off = 1; off < 256; off <<= 1) {
        int u = (t >= off) ? s[t - off] : 0;
        __syncthreads();
        s[t] += u;
        __syncthreads();
    }
    if (t < SB) bsum[t] = s[t] - v;            // exclusive block offsets
    for (int i = t; i < NUM_GRAPHS * HIDDEN; i += 256) add_pool[i] = 0.0f;
}

// ---- Pass 2c: add block offsets -> final ptr; init cur = ptr ---------------
__global__ void scan3(int* __restrict__ ptr, const int* __restrict__ bsum,
                      int* __restrict__ cur) {
    int idx = blockIdx.x * 1024 + threadIdx.x;
    if (idx <= N_NODES) {
        int p = ptr[idx] + bsum[idx >> 10];
        ptr[idx] = p;
        if (idx < N_NODES) cur[idx] = p;
    }
}

// ---- Pass 3: scatter edges into per-node lists (atomic-return cursor) ------
__global__ void scatter_k(const int* __restrict__ src, const int* __restrict__ dst,
                          int* __restrict__ cur, int* __restrict__ esrc) {
    int t = threadIdx.x, b = blockIdx.x;
    int i0 = b * EPB, i1 = min(i0 + EPB, NI4);
    for (int i = i0 + t; i < i1; i += 256) {
        int4 s4 = ((const int4*)src)[i];
        int4 d4 = ((const int4*)dst)[i];
        int r;
        r = atomicAdd(&cur[d4.x], 1); esrc[r] = s4.x;
        r = atomicAdd(&cur[d4.y], 1); esrc[r] = s4.y;
        r = atomicAdd(&cur[d4.z], 1); esrc[r] = s4.z;
        r = atomicAdd(&cur[d4.w], 1); esrc[r] = s4.w;
    }
}

// ==================== GNN compute ===========================================

// ---- Layer 1: 16-lane-group gather (4 nodes/wave) + transform --------------
__global__ void gather_mlp1(const uint4* __restrict__ xb,
                            const float* __restrict__ x,
                            const int* __restrict__ ptr,
                            const int* __restrict__ esrc,
                            const float* __restrict__ w_rel1,
                            const float* __restrict__ b_rel1,
                            const float* __restrict__ w_root1,
                            unsigned short* __restrict__ h1,
                            unsigned char* __restrict__ h1f8) {
    int t    = threadIdx.x;
    int ql   = t & 15;
    int grp  = (blockIdx.x * blockDim.x + t) >> 4;
    int ngrp = (gridDim.x * blockDim.x) >> 4;

    float wr[IN_DIM][4], wo[IN_DIM][4], bias[4];
#pragma unroll
    for (int j = 0; j < 4; ++j) {
        int ch = ql * 4 + j;
        bias[j] = b_rel1[ch];
#pragma unroll
        for (int k = 0; k < IN_DIM; ++k) {
            wr[k][j] = w_rel1[k * HIDDEN + ch];
            wo[k][j] = w_root1[k * HIDDEN + ch];
        }
    }

    for (int n = grp; n < N_NODES; n += ngrp) {
        int start = ptr[n], end = ptr[n + 1];
        float a[IN_DIM] = {0.f, 0.f, 0.f, 0.f, 0.f};
        for (int e = start + ql; e < end; e += 16) {
            uint4 p = xb[esrc[e]];
            a[0] += blo(p.x); a[1] += bhi(p.x);
            a[2] += blo(p.y); a[3] += bhi(p.y);
            a[4] += blo(p.z);
        }
#pragma unroll
        for (int k = 0; k < IN_DIM; ++k) {
            a[k] += __shfl_xor(a[k], 1, 64);
            a[k] += __shfl_xor(a[k], 2, 64);
            a[k] += __shfl_xor(a[k], 4, 64);
            a[k] += __shfl_xor(a[k], 8, 64);
        }
        float xr[IN_DIM];
#pragma unroll
        for (int k = 0; k < IN_DIM; ++k) xr[k] = x[(size_t)n * IN_DIM + k];

        unsigned short hv[4];
        unsigned char  hf[4];
#pragma unroll
        for (int j = 0; j < 4; ++j) {
            float acc = bias[j];
#pragma unroll
            for (int k = 0; k < IN_DIM; ++k)
                acc += a[k] * wr[k][j] + xr[k] * wo[k][j];
            float h = fmaxf(acc, 0.0f);
            hv[j] = f2bs(h);
            hf[j] = f2f8(h);
        }
        ushort4 v4; v4.x = hv[0]; v4.y = hv[1]; v4.z = hv[2]; v4.w = hv[3];
        *(ushort4*)(h1 + (size_t)n * HIDDEN + ql * 4) = v4;
        uchar4 c4; c4.x = hf[0]; c4.y = hf[1]; c4.z = hf[2]; c4.w = hf[3];
        *(uchar4*)(h1f8 + (size_t)n * HIDDEN + ql * 4) = c4;
    }
}

// ---- Layer 2: 16-lane-group fp8-row gather (4 nodes/wave, NO shuffles) -----
__global__ void gather2_fp8(const unsigned* __restrict__ rows,   // row = 16 dwords
                            const int* __restrict__ ptr,
                            const int* __restrict__ esrc,
                            uint2* __restrict__ agg2) {          // row = 16 uint2
    int t    = threadIdx.x;
    int ql   = t & 15;
    int grp  = (blockIdx.x * blockDim.x + t) >> 4;
    int ngrp = (gridDim.x * blockDim.x) >> 4;

    for (int n = grp; n < N_NODES; n += ngrp) {
        int start = ptr[n], end = ptr[n + 1];
        float4 a = {0.f, 0.f, 0.f, 0.f};
        float4 b = {0.f, 0.f, 0.f, 0.f};
        int e = start;
        for (; e + 1 < end; e += 2) {
            int s0 = esrc[e], s1 = esrc[e + 1];
            unsigned r0 = rows[(size_t)s0 * 16 + ql];
            unsigned r1 = rows[(size_t)s1 * 16 + ql];
            a.x += f82f(r0); a.y += f82f(r0 >> 8); a.z += f82f(r0 >> 16); a.w += f82f(r0 >> 24);
            b.x += f82f(r1); b.y += f82f(r1 >> 8); b.z += f82f(r1 >> 16); b.w += f82f(r1 >> 24);
        }
        if (e < end) {
            unsigned r0 = rows[(size_t)esrc[e] * 16 + ql];
            a.x += f82f(r0); a.y += f82f(r0 >> 8); a.z += f82f(r0 >> 16); a.w += f82f(r0 >> 24);
        }
        a.x += b.x; a.y += b.y; a.z += b.z; a.w += b.w;
        uint2 o;
        o.x = pack2(a.x, a.y);
        o.y = pack2(a.z, a.w);
        agg2[(size_t)n * 16 + ql] = o;   // 128B contiguous per node row
    }
}

// ---- Layer 2 transform via MFMA, FUSED with add-pool -----------------------
__global__ void mlp2_pool(const unsigned short* __restrict__ agg2,
                          const unsigned short* __restrict__ h1,
                          const float* __restrict__ w_rel2,
                          const float* __restrict__ b_rel2,
                          const float* __restrict__ w_root2,
                          const int* __restrict__ batch,
                          float* __restrict__ add_pool) {
    int lane = threadIdx.x & 63;
    int wv   = threadIdx.x >> 6;
    int row  = lane & 15;
    int quad = lane >> 4;
    int n    = wv * 16 + row;           // this lane's output column

    short8 bwr[2], bwo[2];
#pragma unroll
    for (int s = 0; s < 2; ++s)
#pragma unroll
        for (int j = 0; j < 8; ++j) {
            int k = 32 * s + quad * 8 + j;
            bwr[s][j] = (short)f2bs(w_rel2[k * HIDDEN + n]);
            bwo[s][j] = (short)f2bs(w_root2[k * HIDDEN + n]);
        }
    float bias = b_rel2[n];

    for (int t = blockIdx.x; t < M_TILES; t += gridDim.x) {
        int m0 = t * 16;
        size_t rbase = (size_t)(m0 + row) * HIDDEN;
        short8 aa0 = *(const short8*)(agg2 + rbase + quad * 8);
        short8 aa1 = *(const short8*)(agg2 + rbase + 32 + quad * 8);
        short8 ah0 = *(const short8*)(h1   + rbase + quad * 8);
        short8 ah1 = *(const short8*)(h1   + rbase + 32 + quad * 8);

        f32x4 acc = {bias, bias, bias, bias};
        acc = __builtin_amdgcn_mfma_f32_16x16x32_bf16(aa0, bwr[0], acc, 0, 0, 0);
        acc = __builtin_amdgcn_mfma_f32_16x16x32_bf16(aa1, bwr[1], acc, 0, 0, 0);
        acc = __builtin_amdgcn_mfma_f32_16x16x32_bf16(ah0, bwo[0], acc, 0, 0, 0);
        acc = __builtin_amdgcn_mfma_f32_16x16x32_bf16(ah1, bwo[1], acc, 0, 0, 0);

        float hv0 = fmaxf(acc[0], 0.0f), hv1 = fmaxf(acc[1], 0.0f);
        float hv2 = fmaxf(acc[2], 0.0f), hv3 = fmaxf(acc[3], 0.0f);

        int gLo = batch[m0], gHi = batch[m0 + 15];
        if (gLo == gHi) {
            float s = (hv0 + hv1) + (hv2 + hv3);
            s += __shfl_xor(s, 16, 64);
            s += __shfl_xor(s, 32, 64);
            if (quad == 0)
                atomicAdd(&add_pool[gLo * HIDDEN + n], s);
        } else {
            int m = m0 + quad * 4;
            atomicAdd(&add_pool[batch[m]     * HIDDEN + n], hv0);
            atomicAdd(&add_pool[batch[m + 1] * HIDDEN + n], hv1);
            atomicAdd(&add_pool[batch[m + 2] * HIDDEN + n], hv2);
            atomicAdd(&add_pool[batch[m + 3] * HIDDEN + n], hv3);
        }
    }
}

// ---- MLP head: one block (64 threads) per graph ----------------------------
__device__ __forceinline__ int lower_bound_i(const int* a, int n, int v) {
    int lo = 0, hi = n;
    while (lo < hi) { int mid = (lo + hi) >> 1; if (a[mid] < v) lo = mid + 1; else hi = mid; }
    return lo;
}

__global__ void head_mlp(const float* __restrict__ add_pool,
                         const int* __restrict__ batch,
                         const float* __restrict__ w_h1,
                         const float* __restrict__ b_h1,
                         const float* __restrict__ w_h2,
                         const float* __restrict__ b_h2,
                         float* __restrict__ out) {
    int g = blockIdx.x, t = threadIdx.x;

    __shared__ int s_cnt;
    if (t == 0) {
        int start = lower_bound_i(batch, N_NODES, g);
        int end   = lower_bound_i(batch, N_NODES, g + 1);
        s_cnt = end - start;
    }
    __syncthreads();
    float cnt = fmaxf((float)s_cnt, 1.0f);

    __shared__ float sg[2 * HIDDEN];
    float add = add_pool[(size_t)g * HIDDEN + t];
    sg[t]          = add / cnt;   // mean_pool
    sg[HIDDEN + t] = add;         // add_pool
    __syncthreads();

    float hid = b_h1[t];
#pragma unroll 16
    for (int i = 0; i < 2 * HIDDEN; ++i)
        hid += sg[i] * w_h1[i * HIDDEN + t];
    hid = fmaxf(hid, 0.0f);

    float res = hid * w_h2[t];
    for (int off = 32; off > 0; off >>= 1)
        res += __shfl_down(res, off, 64);
    if (t == 0) out[g] = res + b_h2[0];
}

extern "C" void kernel_launch(void* const* d_in, const int* in_sizes, int n_in,
                              void* d_out, int out_size, void* d_ws, size_t ws_size,
                              hipStream_t stream) {
    const float* x       = (const float*)d_in[0];
    const int*   ei      = (const int*)d_in[1];
    const int*   src     = ei;
    const int*   dst     = ei + N_EDGES;
    const int*   batch   = (const int*)d_in[2];
    const float* w_rel1  = (const float*)d_in[3];
    const float* b_rel1  = (const float*)d_in[4];
    const float* w_root1 = (const float*)d_in[5];
    const float* w_rel2  = (const float*)d_in[6];
    const float* b_rel2  = (const float*)d_in[7];
    const float* w_root2 = (const float*)d_in[8];
    const float* w_h1    = (const float*)d_in[9];
    const float* b_h1    = (const float*)d_in[10];
    const float* w_h2    = (const float*)d_in[11];
    const float* b_h2    = (const float*)d_in[12];
    float* out = (float*)d_out;

    int* base = (int*)d_ws;
    int*   deg      = base;                                      // N+1
    int*   ptr      = deg + ((N_NODES + 1 + 3) & ~3);            // N+1
    int*   cur      = ptr + ((N_NODES + 1 + 3) & ~3);            // N
    int*   bsum     = cur + ((N_NODES + 3) & ~3);                // SB (round 128)
    float* add_pool = (float*)(bsum + 128);                      // 128*64 f32
    int*   esrc     = (int*)(add_pool + NUM_GRAPHS * HIDDEN);    // E
    unsigned short* h1   = (unsigned short*)(esrc + N_EDGES);    // N*64 bf16
    unsigned short* agg2 = h1 + (size_t)N_NODES * HIDDEN;        // N*64 bf16
    unsigned char*  h1f8 = (unsigned char*)(agg2 + (size_t)N_NODES * HIDDEN); // N*64 fp8
    uint4*          xb   = (uint4*)(h1f8 + (size_t)N_NODES * HIDDEN);         // N*16B

    // ---- CSR build: direct, hierarchical scan (all grid-wide) ----
    zero_k<<<(N_NODES + 1 + 1023) / 1024, 1024, 0, stream>>>(deg);
    deg_xb<<<CBLK, 256, 0, stream>>>(dst, deg, x, xb);
    scan1<<<SB, 1024, 0, stream>>>(deg, ptr, bsum);
    scan2<<<1, 256, 0, stream>>>(bsum, add_pool);
    scan3<<<SB, 1024, 0, stream>>>(ptr, bsum, cur);
    scatter_k<<<CBLK, 256, 0, stream>>>(src, dst, cur, esrc);

    // ---- Layer 1 (16-lane groups, 4 nodes/wave) ----
    gather_mlp1<<<2048, 256, 0, stream>>>(xb, x, ptr, esrc, w_rel1, b_rel1, w_root1, h1, h1f8);
    // ---- Layer 2 gather (16-lane groups, channel-owned lanes) ----
    gather2_fp8<<<2048, 256, 0, stream>>>((const unsigned*)h1f8, ptr, esrc, (uint2*)agg2);
    // ---- Layer 2 transform (MFMA) + add-pool ----
    mlp2_pool<<<2048, 256, 0, stream>>>(agg2, h1, w_rel2, b_rel2, w_root2, batch, add_pool);
    // ---- Head ----
    head_mlp<<<NUM_GRAPHS, 64, 0, stream>>>(add_pool, batch, w_h1, b_h1, w_h2, b_h2, out);
}

// Round 4
// 191.191 us; speedup vs baseline: 3.6349x; 1.5908x over previous
//
#include <hip/hip_runtime.h>
#include <hip/hip_bf16.h>

#define N_NODES    100000
#define N_EDGES    1200000
#define NUM_GRAPHS 128
#define IN_DIM     5
#define HIDDEN     64
#define M_TILES    (N_NODES / 16)   // 6250 (exact)
#define NI4        (N_EDGES / 4)    // 300000 int4 groups

#define CB    391                   // coarse buckets of 256 nodes: ceil(N/256)
#define CBLK  256                   // partition blocks
#define EPB   ((NI4 + CBLK - 1) / CBLK)   // 1172 int4-groups per block

typedef __attribute__((ext_vector_type(8))) short short8;   // 8 bf16 (4 VGPRs)
typedef __attribute__((ext_vector_type(4))) float f32x4;

// fp32 -> bf16 bits (RNE)
__device__ __forceinline__ unsigned short f2bs(float f) {
    union { float f; unsigned u; } v; v.f = f;
    return (unsigned short)((v.u + 0x7FFFu + ((v.u >> 16) & 1u)) >> 16);
}
// bf16 bits -> fp32
__device__ __forceinline__ float bs2f(unsigned short s) {
    union { unsigned u; float f; } v; v.u = ((unsigned)s) << 16;
    return v.f;
}
__device__ __forceinline__ float blo(unsigned p) { return bs2f((unsigned short)(p & 0xffff)); }
__device__ __forceinline__ float bhi(unsigned p) { return bs2f((unsigned short)(p >> 16)); }
__device__ __forceinline__ unsigned pack2(float a, float b) {
    return ((unsigned)f2bs(b) << 16) | (unsigned)f2bs(a);
}

// fp32 (>=0) -> fp8 e4m3 bits, RNE, denorm-exact (magic-multiply trick)
__device__ __forceinline__ unsigned char f2f8(float f) {
    union { float f; unsigned u; } v; v.f = f * 0x1p-120f;
    unsigned u = v.u + 0x7FFFFu + ((v.u >> 20) & 1u);
    return (unsigned char)(u >> 20);
}
// fp8 e4m3 bits -> fp32 (exact inverse)
__device__ __forceinline__ float f82f(unsigned b) {
    union { unsigned u; float f; } v; v.u = (b & 0x7Fu) << 20;
    return v.f * 0x1p120f;
}

// ==================== CSR build: two-level counting sort ====================
// Key property: every block writes part/esrc into PRIVATE contiguous regions
// -> writeback amplification ~1 (vs 17x for the global-cursor scatter, r3).
// part entries are PACKED 4B: src (bits 0..16) | (dst & 255) << 17.

// ---- Pass A: coarse histogram (dst>>8, LDS) + xb pack fold -----------------
__global__ void coarse_count(const int* __restrict__ dst, int* __restrict__ gcnt,
                             const float* __restrict__ x, uint4* __restrict__ xb) {
    __shared__ int h[CB];
    int t = threadIdx.x, b = blockIdx.x;
    for (int i = t; i < CB; i += 256) h[i] = 0;
    __syncthreads();
    int i0 = b * EPB, i1 = min(i0 + EPB, NI4);
    for (int i = i0 + t; i < i1; i += 256) {
        int4 d = ((const int4*)dst)[i];
        atomicAdd(&h[d.x >> 8], 1);
        atomicAdd(&h[d.y >> 8], 1);
        atomicAdd(&h[d.z >> 8], 1);
        atomicAdd(&h[d.w >> 8], 1);
    }
    __syncthreads();
    for (int i = t; i < CB; i += 256) gcnt[b * CB + i] = h[i];

    // fold: pack x rows into 16B (5 bf16 + pad) for the layer-1 edge gather
    for (int n = b * 256 + t; n < N_NODES; n += CBLK * 256) {
        const float* xr = x + (size_t)n * IN_DIM;
        uint4 o;
        o.x = pack2(xr[0], xr[1]);
        o.y = pack2(xr[2], xr[3]);
        o.z = pack2(xr[4], 0.0f);
        o.w = 0u;
        xb[n] = o;
    }
}

// ---- Pass B1: per-bucket exclusive scan over the 256 partition blocks ------
__global__ void block_scan(int* __restrict__ gcnt, int* __restrict__ btot) {
    __shared__ int s[CBLK];
    int k = blockIdx.x, t = threadIdx.x;
    int v = gcnt[t * CB + k];
    s[t] = v;
    __syncthreads();
    for (int off = 1; off < CBLK; off <<= 1) {
        int u = (t >= off) ? s[t - off] : 0;
        __syncthreads();
        s[t] += u;
        __syncthreads();
    }
    gcnt[t * CB + k] = s[t] - v;
    if (t == CBLK - 1) btot[k] = s[t];
}

// ---- Pass B2: scan bucket totals -> bstart; zero add_pool; ptr[N]=E --------
__global__ void bucket_scan(const int* __restrict__ btot, int* __restrict__ bstart,
                            float* __restrict__ add_pool, int* __restrict__ ptr) {
    __shared__ int s[512];
    int t = threadIdx.x;
    int v = (t < CB) ? btot[t] : 0;
    s[t] = v;
    __syncthreads();
    for (int off = 1; off < 512; off <<= 1) {
        int u = (t >= off) ? s[t - off] : 0;
        __syncthreads();
        s[t] += u;
        __syncthreads();
    }
    if (t < CB) bstart[t] = s[t] - v;
    if (t == 0) { bstart[CB] = N_EDGES; ptr[N_NODES] = N_EDGES; }
    for (int i = t; i < NUM_GRAPHS * HIDDEN; i += 512) add_pool[i] = 0.0f;
}

// ---- Pass C: partition edges into coarse-bucket order (packed 4B) ----------
__global__ void partition_k(const int* __restrict__ src, const int* __restrict__ dst,
                            const int* __restrict__ gcnt, const int* __restrict__ bstart,
                            int* __restrict__ part) {
    __shared__ int base[CB];
    __shared__ int h[CB];
    int t = threadIdx.x, b = blockIdx.x;
    for (int i = t; i < CB; i += 256) {
        base[i] = bstart[i] + gcnt[b * CB + i];
        h[i] = 0;
    }
    __syncthreads();
    int i0 = b * EPB, i1 = min(i0 + EPB, NI4);
    for (int i = i0 + t; i < i1; i += 256) {
        int4 s4 = ((const int4*)src)[i];
        int4 d4 = ((const int4*)dst)[i];
        int k, r;
        k = d4.x >> 8; r = atomicAdd(&h[k], 1); part[base[k] + r] = s4.x | ((d4.x & 255) << 17);
        k = d4.y >> 8; r = atomicAdd(&h[k], 1); part[base[k] + r] = s4.y | ((d4.y & 255) << 17);
        k = d4.z >> 8; r = atomicAdd(&h[k], 1); part[base[k] + r] = s4.z | ((d4.z & 255) << 17);
        k = d4.w >> 8; r = atomicAdd(&h[k], 1); part[base[k] + r] = s4.w | ((d4.w & 255) << 17);
    }
}

// ---- Pass D: fine sort within each 256-node bucket, FUSED ptr build --------
// One block owns one bucket: hist -> block scan -> write ptr (coalesced)
// -> scatter esrc into the bucket's private contiguous region.
__global__ void fine_sort(const int* __restrict__ part, const int* __restrict__ bstart,
                          int* __restrict__ ptr, int* __restrict__ esrc) {
    __shared__ int fh[256];   // counts, then exclusive offsets
    __shared__ int fo[256];   // scan workspace
    __shared__ int fr[256];   // scatter cursors
    int k = blockIdx.x, t = threadIdx.x;
    int e0 = bstart[k], e1 = bstart[k + 1];
    fh[t] = 0; fr[t] = 0;
    __syncthreads();
    for (int e = e0 + t; e < e1; e += 256)
        atomicAdd(&fh[(part[e] >> 17) & 255], 1);
    __syncthreads();
    int v = fh[t];
    fo[t] = v;
    __syncthreads();
    for (int off = 1; off < 256; off <<= 1) {
        int u = (t >= off) ? fo[t - off] : 0;
        __syncthreads();
        fo[t] += u;
        __syncthreads();
    }
    int excl = fo[t] - v;
    int n = (k << 8) + t;
    if (n < N_NODES) ptr[n] = e0 + excl;
    fh[t] = excl;
    __syncthreads();
    for (int e = e0 + t; e < e1; e += 256) {
        int p = part[e];
        int d = (p >> 17) & 255;
        int r = atomicAdd(&fr[d], 1);
        esrc[e0 + fh[d] + r] = p & 0x1FFFF;
    }
}

// ==================== GNN compute ===========================================

// ---- Layer 1: 16-lane-group gather (4 nodes/wave) + transform --------------
__global__ void gather_mlp1(const uint4* __restrict__ xb,
                            const float* __restrict__ x,
                            const int* __restrict__ ptr,
                            const int* __restrict__ esrc,
                            const float* __restrict__ w_rel1,
                            const float* __restrict__ b_rel1,
                            const float* __restrict__ w_root1,
                            unsigned short* __restrict__ h1,
                            unsigned char* __restrict__ h1f8) {
    int t    = threadIdx.x;
    int ql   = t & 15;
    int grp  = (blockIdx.x * blockDim.x + t) >> 4;
    int ngrp = (gridDim.x * blockDim.x) >> 4;

    float wr[IN_DIM][4], wo[IN_DIM][4], bias[4];
#pragma unroll
    for (int j = 0; j < 4; ++j) {
        int ch = ql * 4 + j;
        bias[j] = b_rel1[ch];
#pragma unroll
        for (int k = 0; k < IN_DIM; ++k) {
            wr[k][j] = w_rel1[k * HIDDEN + ch];
            wo[k][j] = w_root1[k * HIDDEN + ch];
        }
    }

    for (int n = grp; n < N_NODES; n += ngrp) {
        int start = ptr[n], end = ptr[n + 1];
        float a[IN_DIM] = {0.f, 0.f, 0.f, 0.f, 0.f};
        for (int e = start + ql; e < end; e += 16) {
            uint4 p = xb[esrc[e]];
            a[0] += blo(p.x); a[1] += bhi(p.x);
            a[2] += blo(p.y); a[3] += bhi(p.y);
            a[4] += blo(p.z);
        }
#pragma unroll
        for (int k = 0; k < IN_DIM; ++k) {
            a[k] += __shfl_xor(a[k], 1, 64);
            a[k] += __shfl_xor(a[k], 2, 64);
            a[k] += __shfl_xor(a[k], 4, 64);
            a[k] += __shfl_xor(a[k], 8, 64);
        }
        float xr[IN_DIM];
#pragma unroll
        for (int k = 0; k < IN_DIM; ++k) xr[k] = x[(size_t)n * IN_DIM + k];

        unsigned short hv[4];
        unsigned char  hf[4];
#pragma unroll
        for (int j = 0; j < 4; ++j) {
            float acc = bias[j];
#pragma unroll
            for (int k = 0; k < IN_DIM; ++k)
                acc += a[k] * wr[k][j] + xr[k] * wo[k][j];
            float h = fmaxf(acc, 0.0f);
            hv[j] = f2bs(h);
            hf[j] = f2f8(h);
        }
        ushort4 v4; v4.x = hv[0]; v4.y = hv[1]; v4.z = hv[2]; v4.w = hv[3];
        *(ushort4*)(h1 + (size_t)n * HIDDEN + ql * 4) = v4;
        uchar4 c4; c4.x = hf[0]; c4.y = hf[1]; c4.z = hf[2]; c4.w = hf[3];
        *(uchar4*)(h1f8 + (size_t)n * HIDDEN + ql * 4) = c4;
    }
}

// ---- Layer 2: 16-lane-group fp8-row gather (4 nodes/wave, NO shuffles) -----
__global__ void gather2_fp8(const unsigned* __restrict__ rows,   // row = 16 dwords
                            const int* __restrict__ ptr,
                            const int* __restrict__ esrc,
                            uint2* __restrict__ agg2) {          // row = 16 uint2
    int t    = threadIdx.x;
    int ql   = t & 15;
    int grp  = (blockIdx.x * blockDim.x + t) >> 4;
    int ngrp = (gridDim.x * blockDim.x) >> 4;

    for (int n = grp; n < N_NODES; n += ngrp) {
        int start = ptr[n], end = ptr[n + 1];
        float4 a = {0.f, 0.f, 0.f, 0.f};
        float4 b = {0.f, 0.f, 0.f, 0.f};
        int e = start;
        for (; e + 1 < end; e += 2) {
            int s0 = esrc[e], s1 = esrc[e + 1];
            unsigned r0 = rows[(size_t)s0 * 16 + ql];
            unsigned r1 = rows[(size_t)s1 * 16 + ql];
            a.x += f82f(r0); a.y += f82f(r0 >> 8); a.z += f82f(r0 >> 16); a.w += f82f(r0 >> 24);
            b.x += f82f(r1); b.y += f82f(r1 >> 8); b.z += f82f(r1 >> 16); b.w += f82f(r1 >> 24);
        }
        if (e < end) {
            unsigned r0 = rows[(size_t)esrc[e] * 16 + ql];
            a.x += f82f(r0); a.y += f82f(r0 >> 8); a.z += f82f(r0 >> 16); a.w += f82f(r0 >> 24);
        }
        a.x += b.x; a.y += b.y; a.z += b.z; a.w += b.w;
        uint2 o;
        o.x = pack2(a.x, a.y);
        o.y = pack2(a.z, a.w);
        agg2[(size_t)n * 16 + ql] = o;   // 128B contiguous per node row
    }
}

// ---- Layer 2 transform via MFMA, FUSED with add-pool -----------------------
__global__ void mlp2_pool(const unsigned short* __restrict__ agg2,
                          const unsigned short* __restrict__ h1,
                          const float* __restrict__ w_rel2,
                          const float* __restrict__ b_rel2,
                          const float* __restrict__ w_root2,
                          const int* __restrict__ batch,
                          float* __restrict__ add_pool) {
    int lane = threadIdx.x & 63;
    int wv   = threadIdx.x >> 6;
    int row  = lane & 15;
    int quad = lane >> 4;
    int n    = wv * 16 + row;           // this lane's output column

    short8 bwr[2], bwo[2];
#pragma unroll
    for (int s = 0; s < 2; ++s)
#pragma unroll
        for (int j = 0; j < 8; ++j) {
            int k = 32 * s + quad * 8 + j;
            bwr[s][j] = (short)f2bs(w_rel2[k * HIDDEN + n]);
            bwo[s][j] = (short)f2bs(w_root2[k * HIDDEN + n]);
        }
    float bias = b_rel2[n];

    for (int t = blockIdx.x; t < M_TILES; t += gridDim.x) {
        int m0 = t * 16;
        size_t rbase = (size_t)(m0 + row) * HIDDEN;
        short8 aa0 = *(const short8*)(agg2 + rbase + quad * 8);
        short8 aa1 = *(const short8*)(agg2 + rbase + 32 + quad * 8);
        short8 ah0 = *(const short8*)(h1   + rbase + quad * 8);
        short8 ah1 = *(const short8*)(h1   + rbase + 32 + quad * 8);

        f32x4 acc = {bias, bias, bias, bias};
        acc = __builtin_amdgcn_mfma_f32_16x16x32_bf16(aa0, bwr[0], acc, 0, 0, 0);
        acc = __builtin_amdgcn_mfma_f32_16x16x32_bf16(aa1, bwr[1], acc, 0, 0, 0);
        acc = __builtin_amdgcn_mfma_f32_16x16x32_bf16(ah0, bwo[0], acc, 0, 0, 0);
        acc = __builtin_amdgcn_mfma_f32_16x16x32_bf16(ah1, bwo[1], acc, 0, 0, 0);

        float hv0 = fmaxf(acc[0], 0.0f), hv1 = fmaxf(acc[1], 0.0f);
        float hv2 = fmaxf(acc[2], 0.0f), hv3 = fmaxf(acc[3], 0.0f);

        int gLo = batch[m0], gHi = batch[m0 + 15];
        if (gLo == gHi) {
            float s = (hv0 + hv1) + (hv2 + hv3);
            s += __shfl_xor(s, 16, 64);
            s += __shfl_xor(s, 32, 64);
            if (quad == 0)
                atomicAdd(&add_pool[gLo * HIDDEN + n], s);
        } else {
            int m = m0 + quad * 4;
            atomicAdd(&add_pool[batch[m]     * HIDDEN + n], hv0);
            atomicAdd(&add_pool[batch[m + 1] * HIDDEN + n], hv1);
            atomicAdd(&add_pool[batch[m + 2] * HIDDEN + n], hv2);
            atomicAdd(&add_pool[batch[m + 3] * HIDDEN + n], hv3);
        }
    }
}

// ---- MLP head: one block (64 threads) per graph ----------------------------
__device__ __forceinline__ int lower_bound_i(const int* a, int n, int v) {
    int lo = 0, hi = n;
    while (lo < hi) { int mid = (lo + hi) >> 1; if (a[mid] < v) lo = mid + 1; else hi = mid; }
    return lo;
}

__global__ void head_mlp(const float* __restrict__ add_pool,
                         const int* __restrict__ batch,
                         const float* __restrict__ w_h1,
                         const float* __restrict__ b_h1,
                         const float* __restrict__ w_h2,
                         const float* __restrict__ b_h2,
                         float* __restrict__ out) {
    int g = blockIdx.x, t = threadIdx.x;

    __shared__ int s_cnt;
    if (t == 0) {
        int start = lower_bound_i(batch, N_NODES, g);
        int end   = lower_bound_i(batch, N_NODES, g + 1);
        s_cnt = end - start;
    }
    __syncthreads();
    float cnt = fmaxf((float)s_cnt, 1.0f);

    __shared__ float sg[2 * HIDDEN];
    float add = add_pool[(size_t)g * HIDDEN + t];
    sg[t]          = add / cnt;   // mean_pool
    sg[HIDDEN + t] = add;         // add_pool
    __syncthreads();

    float hid = b_h1[t];
#pragma unroll 16
    for (int i = 0; i < 2 * HIDDEN; ++i)
        hid += sg[i] * w_h1[i * HIDDEN + t];
    hid = fmaxf(hid, 0.0f);

    float res = hid * w_h2[t];
    for (int off = 32; off > 0; off >>= 1)
        res += __shfl_down(res, off, 64);
    if (t == 0) out[g] = res + b_h2[0];
}

extern "C" void kernel_launch(void* const* d_in, const int* in_sizes, int n_in,
                              void* d_out, int out_size, void* d_ws, size_t ws_size,
                              hipStream_t stream) {
    const float* x       = (const float*)d_in[0];
    const int*   ei      = (const int*)d_in[1];
    const int*   src     = ei;
    const int*   dst     = ei + N_EDGES;
    const int*   batch   = (const int*)d_in[2];
    const float* w_rel1  = (const float*)d_in[3];
    const float* b_rel1  = (const float*)d_in[4];
    const float* w_root1 = (const float*)d_in[5];
    const float* w_rel2  = (const float*)d_in[6];
    const float* b_rel2  = (const float*)d_in[7];
    const float* w_root2 = (const float*)d_in[8];
    const float* w_h1    = (const float*)d_in[9];
    const float* b_h1    = (const float*)d_in[10];
    const float* w_h2    = (const float*)d_in[11];
    const float* b_h2    = (const float*)d_in[12];
    float* out = (float*)d_out;

    int* base = (int*)d_ws;
    int*   gcnt     = base;                                   // CBLK*CB
    int*   btot     = gcnt + ((CBLK * CB + 3) & ~3);          // CB
    int*   bstart   = btot + ((CB + 3) & ~3);                 // CB+1
    float* add_pool = (float*)(bstart + ((CB + 1 + 3) & ~3)); // 128*64 f32
    int*   ptr      = (int*)(add_pool + NUM_GRAPHS * HIDDEN); // N+1
    int*   part     = ptr + ((N_NODES + 1 + 3) & ~3);         // E packed ints
    int*   esrc     = part + N_EDGES;                         // E
    unsigned short* h1   = (unsigned short*)(esrc + N_EDGES); // N*64 bf16
    unsigned short* agg2 = h1 + (size_t)N_NODES * HIDDEN;     // N*64 bf16
    unsigned char*  h1f8 = (unsigned char*)(agg2 + (size_t)N_NODES * HIDDEN); // N*64 fp8
    uint4*          xb   = (uint4*)(h1f8 + (size_t)N_NODES * HIDDEN);         // N*16B

    // ---- CSR build: two-level counting sort (write-locality by design) ----
    coarse_count<<<CBLK, 256, 0, stream>>>(dst, gcnt, x, xb);
    block_scan<<<CB, CBLK, 0, stream>>>(gcnt, btot);
    bucket_scan<<<1, 512, 0, stream>>>(btot, bstart, add_pool, ptr);
    partition_k<<<CBLK, 256, 0, stream>>>(src, dst, gcnt, bstart, part);
    fine_sort<<<CB, 256, 0, stream>>>(part, bstart, ptr, esrc);

    // ---- Layer 1 (16-lane groups, 4 nodes/wave) ----
    gather_mlp1<<<2048, 256, 0, stream>>>(xb, x, ptr, esrc, w_rel1, b_rel1, w_root1, h1, h1f8);
    // ---- Layer 2 gather (16-lane groups, channel-owned lanes) ----
    gather2_fp8<<<2048, 256, 0, stream>>>((const unsigned*)h1f8, ptr, esrc, (uint2*)agg2);
    // ---- Layer 2 transform (MFMA) + add-pool ----
    mlp2_pool<<<2048, 256, 0, stream>>>(agg2, h1, w_rel2, b_rel2, w_root2, batch, add_pool);
    // ---- Head ----
    head_mlp<<<NUM_GRAPHS, 64, 0, stream>>>(add_pool, batch, w_h1, b_h1, w_h2, b_h2, out);
}